// Round 2
// baseline (1091.221 us; speedup 1.0000x reference)
//
#include <hip/hip_runtime.h>
#include <cstdint>

typedef __attribute__((ext_vector_type(8))) short bf16x8;
typedef __attribute__((ext_vector_type(4))) float f32x4;

#define B_ 2
#define N_ 2048
#define IN_DIM_ 512
#define D_ 1024
#define H_ 16

__device__ __forceinline__ unsigned short f2bf(float f) {
  uint32_t u = __float_as_uint(f);
  u = u + 0x7fffu + ((u >> 16) & 1u);
  return (unsigned short)(u >> 16);
}
__device__ __forceinline__ float bf2f(unsigned short b) {
  return __uint_as_float(((uint32_t)b) << 16);
}

// async global->LDS, 16B per lane; lds dst is wave-uniform base (+lane*16 by HW)
__device__ __forceinline__ void gll16(const void* g, void* l) {
  __builtin_amdgcn_global_load_lds(
      (const __attribute__((address_space(1))) uint32_t*)g,
      (__attribute__((address_space(3))) uint32_t*)l, 16, 0, 0);
}

// ---------------- elementwise cast fp32 -> bf16 ----------------
__global__ __launch_bounds__(256) void cast_bf16(const float* __restrict__ X,
                                                 unsigned short* __restrict__ O, int n) {
  int i = (blockIdx.x * 256 + threadIdx.x) * 4;
  if (i + 3 < n) {
    f32x4 v = *(const f32x4*)(X + i);
    uint32_t p0 = (uint32_t)f2bf(v[0]) | ((uint32_t)f2bf(v[1]) << 16);
    uint32_t p1 = (uint32_t)f2bf(v[2]) | ((uint32_t)f2bf(v[3]) << 16);
    *(uint32_t*)(O + i) = p0;
    *(uint32_t*)(O + i + 2) = p1;
  }
}

// ---------------- transpose + cast: W[K][N] fp32 -> WT[N][K] bf16 ----------------
__global__ __launch_bounds__(256) void transpose_cast(const float* __restrict__ W,
                                                      unsigned short* __restrict__ WT,
                                                      int K, int N) {
  __shared__ float t[32][33];
  const int tx = threadIdx.x, ty = threadIdx.y;
  const int x = blockIdx.x * 32 + tx;   // N index
  const int y = blockIdx.y * 32 + ty;   // K index
  #pragma unroll
  for (int i = 0; i < 4; ++i)
    t[ty + i * 8][tx] = W[(size_t)(y + i * 8) * N + x];
  __syncthreads();
  const int ox = blockIdx.y * 32 + tx;  // K index (contiguous out)
  #pragma unroll
  for (int i = 0; i < 4; ++i) {
    const int oy = blockIdx.x * 32 + ty + i * 8; // N index
    WT[(size_t)oy * K + ox] = f2bf(t[tx][ty + i * 8]);
  }
}

// ---------------- embed GEMM: h = X@emb_w + b + pe, bf16 out ----------------
// A = Xbf [4096][512], B = EbT [1024][512], C -> Hbf [4096][1024]
__global__ __launch_bounds__(256) void gemm_embed(
    const unsigned short* __restrict__ Xbf, const unsigned short* __restrict__ EbT,
    const float* __restrict__ emb_b, unsigned short* __restrict__ Hbf) {
  const int tid = threadIdx.x, l = tid & 63, w = tid >> 6;
  const int wm = w >> 1, wn = w & 1;
  const int bm = blockIdx.y * 128, bn = blockIdx.x * 128;
  __shared__ unsigned short As[128 * 32], Bs[128 * 32];
  const unsigned short* Ab = Xbf + (size_t)bm * IN_DIM_;
  const unsigned short* Bb = EbT + (size_t)bn * IN_DIM_;
  f32x4 acc[4][4] = {};
  const int lr = l >> 2, lc = (l & 3) * 8;
  for (int k0 = 0; k0 < IN_DIM_; k0 += 32) {
    #pragma unroll
    for (int i = 0; i < 2; ++i) {
      const int c = w * 2 + i;
      gll16(Ab + (size_t)(c * 16 + lr) * IN_DIM_ + k0 + lc, As + c * 512);
      gll16(Bb + (size_t)(c * 16 + lr) * IN_DIM_ + k0 + lc, Bs + c * 512);
    }
    __syncthreads();
    bf16x8 af[4], bfr[4];
    #pragma unroll
    for (int f = 0; f < 4; ++f) {
      af[f]  = *(const bf16x8*)(As + (wm * 64 + f * 16 + (l & 15)) * 32 + (l >> 4) * 8);
      bfr[f] = *(const bf16x8*)(Bs + (wn * 64 + f * 16 + (l & 15)) * 32 + (l >> 4) * 8);
    }
    #pragma unroll
    for (int fr = 0; fr < 4; ++fr)
      #pragma unroll
      for (int fc = 0; fc < 4; ++fc)
        acc[fr][fc] = __builtin_amdgcn_mfma_f32_16x16x32_bf16(af[fr], bfr[fc], acc[fr][fc], 0, 0, 0);
    __syncthreads();
  }
  const float kF = -0.017988946039015983f; // -2*ln(10000)/1024
  #pragma unroll
  for (int fr = 0; fr < 4; ++fr) {
    #pragma unroll
    for (int fc = 0; fc < 4; ++fc) {
      const int col = bn + wn * 64 + fc * 16 + (l & 15);
      const float eb = emb_b[col];
      const float fac = expf((float)(col >> 1) * kF);
      #pragma unroll
      for (int j = 0; j < 4; ++j) {
        const int row = bm + wm * 64 + fr * 16 + (l >> 4) * 4 + j;
        const float pos = (float)(row & (N_ - 1));
        const float ang = pos * fac;
        const float pe = (col & 1) ? cosf(ang) : sinf(ang);
        float v = acc[fr][fc][j] + eb + pe;
        float o = __shfl_xor(v, 1);
        unsigned short mb = f2bf(v), ob = f2bf(o);
        uint32_t pk = (l & 1) ? ((uint32_t)ob | ((uint32_t)mb << 16))
                              : ((uint32_t)mb | ((uint32_t)ob << 16));
        const bool mine = (l & 1) ? (j >= 2) : (j < 2);
        if (mine)
          *(uint32_t*)(Hbf + (size_t)row * D_ + (col & ~1)) = pk;
      }
    }
  }
}

// ---------------- generic NT GEMM 128x128 tile, bf16 out ----------------
// O[z][row][col] = sum_k A[z][row][k] * B[z][col][k]; ldo = gridDim.x*128
__global__ __launch_bounds__(256) void gemm_nt(
    const unsigned short* __restrict__ A, const unsigned short* __restrict__ Bm,
    unsigned short* __restrict__ O, int K, long aZ, long bZ, long oZ) {
  const int z = blockIdx.z;
  const int tid = threadIdx.x, l = tid & 63, w = tid >> 6;
  const int wm = w >> 1, wn = w & 1;
  const int bm = blockIdx.y * 128, bn = blockIdx.x * 128;
  const int ldo = gridDim.x * 128;
  __shared__ unsigned short As[128 * 32], Bs[128 * 32];
  const unsigned short* Ab = A + (size_t)z * aZ + (size_t)bm * K;
  const unsigned short* Bb = Bm + (size_t)z * bZ + (size_t)bn * K;
  f32x4 acc[4][4] = {};
  const int lr = l >> 2, lc = (l & 3) * 8;
  for (int k0 = 0; k0 < K; k0 += 32) {
    #pragma unroll
    for (int i = 0; i < 2; ++i) {
      const int c = w * 2 + i;
      gll16(Ab + (size_t)(c * 16 + lr) * K + k0 + lc, As + c * 512);
      gll16(Bb + (size_t)(c * 16 + lr) * K + k0 + lc, Bs + c * 512);
    }
    __syncthreads();
    bf16x8 af[4], bfr[4];
    #pragma unroll
    for (int f = 0; f < 4; ++f) {
      af[f]  = *(const bf16x8*)(As + (wm * 64 + f * 16 + (l & 15)) * 32 + (l >> 4) * 8);
      bfr[f] = *(const bf16x8*)(Bs + (wn * 64 + f * 16 + (l & 15)) * 32 + (l >> 4) * 8);
    }
    #pragma unroll
    for (int fr = 0; fr < 4; ++fr)
      #pragma unroll
      for (int fc = 0; fc < 4; ++fc)
        acc[fr][fc] = __builtin_amdgcn_mfma_f32_16x16x32_bf16(af[fr], bfr[fc], acc[fr][fc], 0, 0, 0);
    __syncthreads();
  }
  unsigned short* obase = O + (size_t)z * oZ;
  #pragma unroll
  for (int fr = 0; fr < 4; ++fr) {
    #pragma unroll
    for (int fc = 0; fc < 4; ++fc) {
      const int col = bn + wn * 64 + fc * 16 + (l & 15);
      #pragma unroll
      for (int j = 0; j < 4; ++j) {
        const int row = bm + wm * 64 + fr * 16 + (l >> 4) * 4 + j;
        float v = acc[fr][fc][j];
        float o = __shfl_xor(v, 1);
        unsigned short mb = f2bf(v), ob = f2bf(o);
        uint32_t pk = (l & 1) ? ((uint32_t)ob | ((uint32_t)mb << 16))
                              : ((uint32_t)mb | ((uint32_t)ob << 16));
        const bool mine = (l & 1) ? (j >= 2) : (j < 2);
        if (mine)
          *(uint32_t*)(obase + (size_t)row * ldo + (col & ~1)) = pk;
      }
    }
  }
}

// ---------------- V = h @ Wv (per head), fp32 ----------------
__global__ __launch_bounds__(256) void v_kernel(
    const unsigned short* __restrict__ Hbf, const float* __restrict__ Wv,
    float* __restrict__ V) {
  const int l = threadIdx.x & 63, w = threadIdx.x >> 6;
  const int ng = blockIdx.x * 4 + w;          // [0, 4096)
  const int b = ng >> 11, n = ng & (N_ - 1);
  const unsigned short* hr = Hbf + (size_t)ng * D_;
  float hv[16];
  #pragma unroll
  for (int i = 0; i < 2; ++i) {
    bf16x8 x = *(const bf16x8*)(hr + l * 16 + i * 8);
    #pragma unroll
    for (int j = 0; j < 8; ++j) hv[i * 8 + j] = bf2f((unsigned short)x[j]);
  }
  for (int h = 0; h < H_; ++h) {
    const float* wr = Wv + (size_t)h * D_ + l * 16;
    float s = 0.f;
    #pragma unroll
    for (int i = 0; i < 4; ++i) {
      f32x4 w4 = *(const f32x4*)(wr + i * 4);
      s += hv[i*4+0]*w4[0] + hv[i*4+1]*w4[1] + hv[i*4+2]*w4[2] + hv[i*4+3]*w4[3];
    }
    #pragma unroll
    for (int m = 1; m < 64; m <<= 1) s += __shfl_xor(s, m);
    if (l == 0) V[((size_t)b * H_ + h) * N_ + n] = s;
  }
}

// ---------------- fused flash attention: scores = G @ h^T, V scalar per key ----
// grid (N/64, H); block 256 = 4 waves, each wave owns 16 q-rows
// G: [h][2048][1024] bf16 (this batch), Hb: [2048][1024] bf16 (this batch)
__global__ __launch_bounds__(256) void flash_kernel(
    const unsigned short* __restrict__ G, const unsigned short* __restrict__ Hb,
    const float* __restrict__ V, float* __restrict__ ctx) {
  const int tid = threadIdx.x, l = tid & 63, w = tid >> 6;
  const int qb = blockIdx.x, h = blockIdx.y;
  __shared__ unsigned short Ks[4 * 128 * 32];  // [s][128 k-rows][32 d]
  const unsigned short* Gq = G + ((size_t)h * N_ + qb * 64 + w * 16 + (l & 15)) * D_;
  const float* Vbh = V + (size_t)h * N_;

  float mst[4], lsum[4], osum[4];
  #pragma unroll
  for (int j = 0; j < 4; ++j) { mst[j] = -1e30f; lsum[j] = 0.f; osum[j] = 0.f; }

  for (int kt = 0; kt < 16; ++kt) {
    f32x4 acc[8] = {};
    for (int dd = 0; dd < 8; ++dd) {
      #pragma unroll
      for (int i = 0; i < 8; ++i) {
        const int c = w * 8 + i;  // 32 chunks: sub-slice s=c&3, row-chunk c>>2
        gll16(Hb + (size_t)(kt * 128 + (c >> 2) * 16 + (l >> 2)) * D_
                 + dd * 128 + (c & 3) * 32 + (l & 3) * 8,
              Ks + (c & 3) * 4096 + (c >> 2) * 512);
      }
      bf16x8 aq[4];
      #pragma unroll
      for (int s = 0; s < 4; ++s)
        aq[s] = *(const bf16x8*)(Gq + dd * 128 + s * 32 + (l >> 4) * 8);
      __syncthreads();
      #pragma unroll
      for (int s = 0; s < 4; ++s) {
        #pragma unroll
        for (int f = 0; f < 8; ++f) {
          bf16x8 bfr = *(const bf16x8*)(Ks + s * 4096 + (f * 16 + (l & 15)) * 32 + (l >> 4) * 8);
          acc[f] = __builtin_amdgcn_mfma_f32_16x16x32_bf16(aq[s], bfr, acc[f], 0, 0, 0);
        }
      }
      __syncthreads();
    }
    // online softmax update (state per q-row j, replicated across 16-lane groups)
    float vv[8];
    #pragma unroll
    for (int f = 0; f < 8; ++f) vv[f] = Vbh[kt * 128 + f * 16 + (l & 15)];
    #pragma unroll
    for (int j = 0; j < 4; ++j) {
      float s8[8];
      #pragma unroll
      for (int f = 0; f < 8; ++f) s8[f] = acc[f][j] * 0.03125f;
      if (kt == 0 && (l & 15) == 0) s8[0] = 0.0f;  // multiplicative mask col 0
      float tm = s8[0];
      #pragma unroll
      for (int f = 1; f < 8; ++f) tm = fmaxf(tm, s8[f]);
      tm = fmaxf(tm, __shfl_xor(tm, 1));
      tm = fmaxf(tm, __shfl_xor(tm, 2));
      tm = fmaxf(tm, __shfl_xor(tm, 4));
      tm = fmaxf(tm, __shfl_xor(tm, 8));
      const float mo = mst[j];
      const float mn = fmaxf(mo, tm);
      const float corr = expf(mo - mn);
      float ps = 0.f, pv = 0.f;
      #pragma unroll
      for (int f = 0; f < 8; ++f) {
        const float e = expf(s8[f] - mn);
        ps += e; pv += e * vv[f];
      }
      ps += __shfl_xor(ps, 1); pv += __shfl_xor(pv, 1);
      ps += __shfl_xor(ps, 2); pv += __shfl_xor(pv, 2);
      ps += __shfl_xor(ps, 4); pv += __shfl_xor(pv, 4);
      ps += __shfl_xor(ps, 8); pv += __shfl_xor(pv, 8);
      lsum[j] = lsum[j] * corr + ps;
      osum[j] = osum[j] * corr + pv;
      mst[j] = mn;
    }
  }
  if ((l & 15) == 0) {
    #pragma unroll
    for (int j = 0; j < 4; ++j) {
      const int q = qb * 64 + w * 16 + (l >> 4) * 4 + j;
      ctx[(size_t)q * H_ + h] = osum[j] / lsum[j];
    }
  }
}

// ---------------- M = Wo @ dec_w  [16][1024] fp32 ----------------
__global__ __launch_bounds__(256) void wodec_kernel(
    const float* __restrict__ Wo, const float* __restrict__ dec_w, float* __restrict__ M) {
  const int idx = blockIdx.x * 256 + threadIdx.x;
  const int h = idx >> 10, c = idx & 1023;
  float s = 0.f;
  #pragma unroll 4
  for (int d = 0; d < D_; ++d) s += Wo[h * D_ + d] * dec_w[(size_t)d * 1024 + c];
  M[idx] = s;
}

// ---------------- out = ctx @ M + dec_b ----------------
__global__ __launch_bounds__(256) void final_kernel(
    const float* __restrict__ ctx, const float* __restrict__ M,
    const float* __restrict__ dec_b, float* __restrict__ out) {
  const int idx = blockIdx.x * 256 + threadIdx.x;
  const int c = idx & 1023;
  const float* cr = ctx + (size_t)(idx >> 10) * H_;
  float s = dec_b[c];
  #pragma unroll
  for (int h = 0; h < H_; ++h) s += cr[h] * M[h * 1024 + c];
  out[idx] = s;
}

extern "C" void kernel_launch(void* const* d_in, const int* in_sizes, int n_in,
                              void* d_out, int out_size, void* d_ws, size_t ws_size,
                              hipStream_t stream) {
  const float* X     = (const float*)d_in[0];
  const float* emb_w = (const float*)d_in[1];
  const float* emb_b = (const float*)d_in[2];
  const float* Wq    = (const float*)d_in[3];
  const float* Wk    = (const float*)d_in[4];
  const float* Wv    = (const float*)d_in[5];
  const float* Wo    = (const float*)d_in[6];
  const float* dec_b = (const float*)d_in[8];
  const float* dec_w = (const float*)d_in[7];
  float* out = (float*)d_out;
  (void)in_sizes; (void)n_in; (void)out_size;

  char* ws = (char*)d_ws;
  // persistent region: 41 MB
  unsigned short* Hbf = (unsigned short*)(ws);                              // 8 MB  [4096][1024]
  unsigned short* Wkq = (unsigned short*)(ws + ((size_t)8 << 20));          // 32 MB [16][1024][1024]
  float* Vb  = (float*)(ws + ((size_t)40 << 20));                          // 256 KB [2][16][2048]
  float* ctx = (float*)(ws + ((size_t)40 << 20) + ((size_t)256 << 10));    // 256 KB [4096][16]
  float* Mw  = (float*)(ws + ((size_t)40 << 20) + ((size_t)512 << 10));    // 64 KB  [16][1024]
  // scratch region S (64 MB), phase-aliased
  char* S = ws + ((size_t)41 << 20);
  unsigned short* Xbf  = (unsigned short*)(S);                              // 4 MB
  unsigned short* EbT  = (unsigned short*)(S + ((size_t)4 << 20));          // 1 MB
  unsigned short* Wqbf = (unsigned short*)(S);                              // 32 MB
  unsigned short* Wkbf = (unsigned short*)(S + ((size_t)32 << 20));         // 32 MB
  unsigned short* G    = (unsigned short*)(S);                              // 64 MB [16][2048][1024]

  const size_t need = ((size_t)41 << 20) + ((size_t)64 << 20);  // 105 MB
  if (ws_size < need) return;  // clean fail -> diagnostic (ws too small)

  cast_bf16<<<2048, 256, 0, stream>>>(X, Xbf, B_ * N_ * IN_DIM_);
  transpose_cast<<<dim3(32, 16, 1), dim3(32, 8), 0, stream>>>(emb_w, EbT, IN_DIM_, D_);
  gemm_embed<<<dim3(8, 32), 256, 0, stream>>>(Xbf, EbT, emb_b, Hbf);
  // Wkq[h] = Wk[h] @ Wq[h]^T  (so that G = h @ Wkq^T = h @ (Wq Wk^T))
  cast_bf16<<<16384, 256, 0, stream>>>(Wq, Wqbf, H_ * D_ * D_);
  cast_bf16<<<16384, 256, 0, stream>>>(Wk, Wkbf, H_ * D_ * D_);
  gemm_nt<<<dim3(8, 8, 16), 256, 0, stream>>>(Wkbf, Wqbf, Wkq, D_,
                                              (long)D_ * D_, (long)D_ * D_, (long)D_ * D_);
  v_kernel<<<1024, 256, 0, stream>>>(Hbf, Wv, Vb);
  wodec_kernel<<<64, 256, 0, stream>>>(Wo, dec_w, Mw);

  for (int b = 0; b < B_; ++b) {
    const unsigned short* Hb = Hbf + (size_t)b * N_ * D_;
    // G[h] = Hb @ Wkq[h]^T   [16][2048][1024]
    gemm_nt<<<dim3(8, 16, 16), 256, 0, stream>>>(Hb, Wkq, G, D_,
                                                 0L, (long)D_ * D_, (long)N_ * D_);
    flash_kernel<<<dim3(32, 16), 256, 0, stream>>>(G, Hb, Vb + (size_t)b * H_ * N_,
                                                   ctx + (size_t)b * N_ * H_);
  }
  final_kernel<<<16384, 256, 0, stream>>>(ctx, Mw, dec_b, out);
}

// Round 3
// 966.497 us; speedup vs baseline: 1.1290x; 1.1290x over previous
//
#include <hip/hip_runtime.h>
#include <cstdint>

typedef __attribute__((ext_vector_type(8))) short bf16x8;
typedef __attribute__((ext_vector_type(4))) float f32x4;

#define B_ 2
#define N_ 2048
#define IN_DIM_ 512
#define D_ 1024
#define H_ 16

__device__ __forceinline__ unsigned short f2bf(float f) {
  uint32_t u = __float_as_uint(f);
  u = u + 0x7fffu + ((u >> 16) & 1u);
  return (unsigned short)(u >> 16);
}
__device__ __forceinline__ float bf2f(unsigned short b) {
  return __uint_as_float(((uint32_t)b) << 16);
}

// async global->LDS, 16B per lane; lds dst is wave-uniform base (+lane*16 by HW)
__device__ __forceinline__ void gll16(const void* g, void* l) {
  __builtin_amdgcn_global_load_lds(
      (const __attribute__((address_space(1))) uint32_t*)g,
      (__attribute__((address_space(3))) uint32_t*)l, 16, 0, 0);
}

// ---------------- elementwise cast fp32 -> bf16 ----------------
__global__ __launch_bounds__(256) void cast_bf16(const float* __restrict__ X,
                                                 unsigned short* __restrict__ O, int n) {
  int i = (blockIdx.x * 256 + threadIdx.x) * 4;
  if (i + 3 < n) {
    f32x4 v = *(const f32x4*)(X + i);
    uint32_t p0 = (uint32_t)f2bf(v[0]) | ((uint32_t)f2bf(v[1]) << 16);
    uint32_t p1 = (uint32_t)f2bf(v[2]) | ((uint32_t)f2bf(v[3]) << 16);
    *(uint32_t*)(O + i) = p0;
    *(uint32_t*)(O + i + 2) = p1;
  }
}

// ---------------- transpose + cast: W[K][N] fp32 -> WT[N][K] bf16 ----------------
__global__ __launch_bounds__(256) void transpose_cast(const float* __restrict__ W,
                                                      unsigned short* __restrict__ WT,
                                                      int K, int N) {
  __shared__ float t[32][33];
  const int tx = threadIdx.x, ty = threadIdx.y;
  const int x = blockIdx.x * 32 + tx;   // N index
  const int y = blockIdx.y * 32 + ty;   // K index
  #pragma unroll
  for (int i = 0; i < 4; ++i)
    t[ty + i * 8][tx] = W[(size_t)(y + i * 8) * N + x];
  __syncthreads();
  const int ox = blockIdx.y * 32 + tx;  // K index (contiguous out)
  #pragma unroll
  for (int i = 0; i < 4; ++i) {
    const int oy = blockIdx.x * 32 + ty + i * 8; // N index
    WT[(size_t)oy * K + ox] = f2bf(t[tx][ty + i * 8]);
  }
}

// ---------------- embed GEMM: h = X@emb_w + b + pe, bf16 out ----------------
__global__ __launch_bounds__(256) void gemm_embed(
    const unsigned short* __restrict__ Xbf, const unsigned short* __restrict__ EbT,
    const float* __restrict__ emb_b, unsigned short* __restrict__ Hbf) {
  const int tid = threadIdx.x, l = tid & 63, w = tid >> 6;
  const int wm = w >> 1, wn = w & 1;
  const int bm = blockIdx.y * 128, bn = blockIdx.x * 128;
  __shared__ unsigned short As[128 * 32], Bs[128 * 32];
  const unsigned short* Ab = Xbf + (size_t)bm * IN_DIM_;
  const unsigned short* Bb = EbT + (size_t)bn * IN_DIM_;
  f32x4 acc[4][4] = {};
  const int lr = l >> 2, lc = (l & 3) * 8;
  for (int k0 = 0; k0 < IN_DIM_; k0 += 32) {
    #pragma unroll
    for (int i = 0; i < 2; ++i) {
      const int c = w * 2 + i;
      gll16(Ab + (size_t)(c * 16 + lr) * IN_DIM_ + k0 + lc, As + c * 512);
      gll16(Bb + (size_t)(c * 16 + lr) * IN_DIM_ + k0 + lc, Bs + c * 512);
    }
    __syncthreads();
    bf16x8 af[4], bfr[4];
    #pragma unroll
    for (int f = 0; f < 4; ++f) {
      af[f]  = *(const bf16x8*)(As + (wm * 64 + f * 16 + (l & 15)) * 32 + (l >> 4) * 8);
      bfr[f] = *(const bf16x8*)(Bs + (wn * 64 + f * 16 + (l & 15)) * 32 + (l >> 4) * 8);
    }
    #pragma unroll
    for (int fr = 0; fr < 4; ++fr)
      #pragma unroll
      for (int fc = 0; fc < 4; ++fc)
        acc[fr][fc] = __builtin_amdgcn_mfma_f32_16x16x32_bf16(af[fr], bfr[fc], acc[fr][fc], 0, 0, 0);
    __syncthreads();
  }
  const float kF = -0.017988946039015983f; // -2*ln(10000)/1024
  #pragma unroll
  for (int fr = 0; fr < 4; ++fr) {
    #pragma unroll
    for (int fc = 0; fc < 4; ++fc) {
      const int col = bn + wn * 64 + fc * 16 + (l & 15);
      const float eb = emb_b[col];
      const float fac = expf((float)(col >> 1) * kF);
      #pragma unroll
      for (int j = 0; j < 4; ++j) {
        const int row = bm + wm * 64 + fr * 16 + (l >> 4) * 4 + j;
        const float pos = (float)(row & (N_ - 1));
        const float ang = pos * fac;
        const float pe = (col & 1) ? cosf(ang) : sinf(ang);
        float v = acc[fr][fc][j] + eb + pe;
        float o = __shfl_xor(v, 1);
        unsigned short mb = f2bf(v), ob = f2bf(o);
        uint32_t pk = (l & 1) ? ((uint32_t)ob | ((uint32_t)mb << 16))
                              : ((uint32_t)mb | ((uint32_t)ob << 16));
        const bool mine = (l & 1) ? (j >= 2) : (j < 2);
        if (mine)
          *(uint32_t*)(Hbf + (size_t)row * D_ + (col & ~1)) = pk;
      }
    }
  }
}

// ---------------- generic NT GEMM 128x128 tile, bf16 out ----------------
__global__ __launch_bounds__(256) void gemm_nt(
    const unsigned short* __restrict__ A, const unsigned short* __restrict__ Bm,
    unsigned short* __restrict__ O, int K, long aZ, long bZ, long oZ) {
  const int z = blockIdx.z;
  const int tid = threadIdx.x, l = tid & 63, w = tid >> 6;
  const int wm = w >> 1, wn = w & 1;
  const int bm = blockIdx.y * 128, bn = blockIdx.x * 128;
  const int ldo = gridDim.x * 128;
  __shared__ unsigned short As[128 * 32], Bs[128 * 32];
  const unsigned short* Ab = A + (size_t)z * aZ + (size_t)bm * K;
  const unsigned short* Bb = Bm + (size_t)z * bZ + (size_t)bn * K;
  f32x4 acc[4][4] = {};
  const int lr = l >> 2, lc = (l & 3) * 8;
  for (int k0 = 0; k0 < K; k0 += 32) {
    #pragma unroll
    for (int i = 0; i < 2; ++i) {
      const int c = w * 2 + i;
      gll16(Ab + (size_t)(c * 16 + lr) * K + k0 + lc, As + c * 512);
      gll16(Bb + (size_t)(c * 16 + lr) * K + k0 + lc, Bs + c * 512);
    }
    __syncthreads();
    bf16x8 af[4], bfr[4];
    #pragma unroll
    for (int f = 0; f < 4; ++f) {
      af[f]  = *(const bf16x8*)(As + (wm * 64 + f * 16 + (l & 15)) * 32 + (l >> 4) * 8);
      bfr[f] = *(const bf16x8*)(Bs + (wn * 64 + f * 16 + (l & 15)) * 32 + (l >> 4) * 8);
    }
    #pragma unroll
    for (int fr = 0; fr < 4; ++fr)
      #pragma unroll
      for (int fc = 0; fc < 4; ++fc)
        acc[fr][fc] = __builtin_amdgcn_mfma_f32_16x16x32_bf16(af[fr], bfr[fc], acc[fr][fc], 0, 0, 0);
    __syncthreads();
  }
  unsigned short* obase = O + (size_t)z * oZ;
  #pragma unroll
  for (int fr = 0; fr < 4; ++fr) {
    #pragma unroll
    for (int fc = 0; fc < 4; ++fc) {
      const int col = bn + wn * 64 + fc * 16 + (l & 15);
      #pragma unroll
      for (int j = 0; j < 4; ++j) {
        const int row = bm + wm * 64 + fr * 16 + (l >> 4) * 4 + j;
        float v = acc[fr][fc][j];
        float o = __shfl_xor(v, 1);
        unsigned short mb = f2bf(v), ob = f2bf(o);
        uint32_t pk = (l & 1) ? ((uint32_t)ob | ((uint32_t)mb << 16))
                              : ((uint32_t)mb | ((uint32_t)ob << 16));
        const bool mine = (l & 1) ? (j >= 2) : (j < 2);
        if (mine)
          *(uint32_t*)(obase + (size_t)row * ldo + (col & ~1)) = pk;
      }
    }
  }
}

// ---------------- V = h @ Wv (per head), fp32 ----------------
__global__ __launch_bounds__(256) void v_kernel(
    const unsigned short* __restrict__ Hbf, const float* __restrict__ Wv,
    float* __restrict__ V) {
  const int l = threadIdx.x & 63, w = threadIdx.x >> 6;
  const int ng = blockIdx.x * 4 + w;          // [0, 4096)
  const int b = ng >> 11, n = ng & (N_ - 1);
  const unsigned short* hr = Hbf + (size_t)ng * D_;
  float hv[16];
  #pragma unroll
  for (int i = 0; i < 2; ++i) {
    bf16x8 x = *(const bf16x8*)(hr + l * 16 + i * 8);
    #pragma unroll
    for (int j = 0; j < 8; ++j) hv[i * 8 + j] = bf2f((unsigned short)x[j]);
  }
  for (int h = 0; h < H_; ++h) {
    const float* wr = Wv + (size_t)h * D_ + l * 16;
    float s = 0.f;
    #pragma unroll
    for (int i = 0; i < 4; ++i) {
      f32x4 w4 = *(const f32x4*)(wr + i * 4);
      s += hv[i*4+0]*w4[0] + hv[i*4+1]*w4[1] + hv[i*4+2]*w4[2] + hv[i*4+3]*w4[3];
    }
    #pragma unroll
    for (int m = 1; m < 64; m <<= 1) s += __shfl_xor(s, m);
    if (l == 0) V[((size_t)b * H_ + h) * N_ + n] = s;
  }
}

// ---------------- fused flash attention v2 ----------------
// grid (N/64, H); block 256 = 4 waves.
// Block computes 64 q-rows x all 2048 k. Each wave: all 64 q x its 128-k slice
// (Rq=4 x Ck=8 outer product: 12 ds_read -> 32 MFMA). kt-tiles of 512 cols.
// LDS per 32-d phase: Q[64][32] (4KB) + K[512][32] (32KB), XOR-swizzled rows.
__global__ __launch_bounds__(256, 2) void flash_kernel(
    const unsigned short* __restrict__ G, const unsigned short* __restrict__ Hb,
    const float* __restrict__ V, float* __restrict__ ctx) {
  const int tid = threadIdx.x, l = tid & 63, w = tid >> 6;
  const int qb = blockIdx.x, h = blockIdx.y;
  __shared__ unsigned short Ks[18432];  // 36 KB: [0,2048)=Q, [2048,18432)=K
  const unsigned short* Gh = G + (size_t)h * N_ * D_;
  const float* Vh = V + (size_t)h * N_;

  const int gsrc = ((l & 3) ^ ((l >> 2) & 3)) * 8;   // inverse-swizzled src chunk (elems)
  const int rchunk = ((l >> 4) ^ (l & 3)) * 8;       // swizzled read chunk (elems)
  const int lr2 = l >> 2;

  float mst[16], lsum[16], osum[16];
  #pragma unroll
  for (int i = 0; i < 16; ++i) { mst[i] = -1e30f; lsum[i] = 0.f; osum[i] = 0.f; }

  for (int kt = 0; kt < 4; ++kt) {
    f32x4 acc[4][8] = {};
    for (int dd = 0; dd < 32; ++dd) {
      // ---- stage phase (kt, dd): 36 chunks of [16 rows][32 d], 9 per wave ----
      #pragma unroll
      for (int i = 0; i < 9; ++i) {
        const int t = w * 9 + i;
        if (t < 4) {  // Q chunk t
          gll16(Gh + (size_t)(qb * 64 + t * 16 + lr2) * D_ + dd * 32 + gsrc,
                Ks + t * 512);
        } else {      // K chunk t-4
          const int u = t - 4;
          gll16(Hb + (size_t)(kt * 512 + u * 16 + lr2) * D_ + dd * 32 + gsrc,
                Ks + 2048 + u * 512);
        }
      }
      __syncthreads();  // drain vmcnt -> staged data visible
      // ---- compute: af[4] x bfr[8] -> 32 MFMA ----
      bf16x8 af[4];
      #pragma unroll
      for (int fr = 0; fr < 4; ++fr)
        af[fr] = *(const bf16x8*)(Ks + fr * 512 + (l & 15) * 32 + rchunk);
      #pragma unroll
      for (int f = 0; f < 8; ++f) {
        bf16x8 bv = *(const bf16x8*)(Ks + 2048 + (w * 8 + f) * 512 + (l & 15) * 32 + rchunk);
        #pragma unroll
        for (int fr = 0; fr < 4; ++fr)
          acc[fr][f] = __builtin_amdgcn_mfma_f32_16x16x32_bf16(af[fr], bv, acc[fr][f], 0, 0, 0);
      }
      __syncthreads();  // all reads done before next stage overwrites
    }
    // ---- online softmax for this kt-tile (wave-local cols kt*512 + w*128 ..) ----
    float vv[8];
    #pragma unroll
    for (int f = 0; f < 8; ++f) vv[f] = Vh[kt * 512 + w * 128 + f * 16 + (l & 15)];
    #pragma unroll
    for (int fr = 0; fr < 4; ++fr) {
      #pragma unroll
      for (int j = 0; j < 4; ++j) {
        const int st = fr * 4 + j;
        float s8[8];
        #pragma unroll
        for (int f = 0; f < 8; ++f) s8[f] = acc[fr][f][j] * 0.03125f;
        if (kt == 0 && w == 0 && (l & 15) == 0) s8[0] = 0.0f;  // mask col 0
        float tm = fmaxf(fmaxf(fmaxf(s8[0], s8[1]), fmaxf(s8[2], s8[3])),
                         fmaxf(fmaxf(s8[4], s8[5]), fmaxf(s8[6], s8[7])));
        tm = fmaxf(tm, __shfl_xor(tm, 1));
        tm = fmaxf(tm, __shfl_xor(tm, 2));
        tm = fmaxf(tm, __shfl_xor(tm, 4));
        tm = fmaxf(tm, __shfl_xor(tm, 8));
        const float mo = mst[st];
        const float mn = fmaxf(mo, tm);
        const float corr = expf(mo - mn);
        float ps = 0.f, pv = 0.f;
        #pragma unroll
        for (int f = 0; f < 8; ++f) {
          const float e = expf(s8[f] - mn);
          ps += e; pv += e * vv[f];
        }
        ps += __shfl_xor(ps, 1); pv += __shfl_xor(pv, 1);
        ps += __shfl_xor(ps, 2); pv += __shfl_xor(pv, 2);
        ps += __shfl_xor(ps, 4); pv += __shfl_xor(pv, 4);
        ps += __shfl_xor(ps, 8); pv += __shfl_xor(pv, 8);
        lsum[st] = lsum[st] * corr + ps;
        osum[st] = osum[st] * corr + pv;
        mst[st] = mn;
      }
    }
  }
  // ---- cross-wave merge: 4 partial (m,l,o) per q-row ----
  float* sb = (float*)Ks;  // [4 waves][64 rows][3] = 3 KB (Ks dead now)
  if ((l & 15) == 0) {
    #pragma unroll
    for (int fr = 0; fr < 4; ++fr)
      #pragma unroll
      for (int j = 0; j < 4; ++j) {
        const int r = fr * 16 + (l >> 4) * 4 + j;
        const int st = fr * 4 + j;
        sb[(w * 64 + r) * 3 + 0] = mst[st];
        sb[(w * 64 + r) * 3 + 1] = lsum[st];
        sb[(w * 64 + r) * 3 + 2] = osum[st];
      }
  }
  __syncthreads();
  if (tid < 64) {
    const int r = tid;
    float m0 = sb[r * 3], m1 = sb[(64 + r) * 3], m2 = sb[(128 + r) * 3], m3 = sb[(192 + r) * 3];
    const float mM = fmaxf(fmaxf(m0, m1), fmaxf(m2, m3));
    const float e0 = expf(m0 - mM), e1 = expf(m1 - mM), e2 = expf(m2 - mM), e3 = expf(m3 - mM);
    const float L = sb[r * 3 + 1] * e0 + sb[(64 + r) * 3 + 1] * e1 +
                    sb[(128 + r) * 3 + 1] * e2 + sb[(192 + r) * 3 + 1] * e3;
    const float O = sb[r * 3 + 2] * e0 + sb[(64 + r) * 3 + 2] * e1 +
                    sb[(128 + r) * 3 + 2] * e2 + sb[(192 + r) * 3 + 2] * e3;
    ctx[(size_t)(qb * 64 + r) * H_ + h] = O / L;
  }
}

// ---------------- M = Wo @ dec_w  [16][1024] fp32 ----------------
__global__ __launch_bounds__(256) void wodec_kernel(
    const float* __restrict__ Wo, const float* __restrict__ dec_w, float* __restrict__ M) {
  const int idx = blockIdx.x * 256 + threadIdx.x;
  const int h = idx >> 10, c = idx & 1023;
  float s = 0.f;
  #pragma unroll 4
  for (int d = 0; d < D_; ++d) s += Wo[h * D_ + d] * dec_w[(size_t)d * 1024 + c];
  M[idx] = s;
}

// ---------------- out = ctx @ M + dec_b ----------------
__global__ __launch_bounds__(256) void final_kernel(
    const float* __restrict__ ctx, const float* __restrict__ M,
    const float* __restrict__ dec_b, float* __restrict__ out) {
  const int idx = blockIdx.x * 256 + threadIdx.x;
  const int c = idx & 1023;
  const float* cr = ctx + (size_t)(idx >> 10) * H_;
  float s = dec_b[c];
  #pragma unroll
  for (int h = 0; h < H_; ++h) s += cr[h] * M[h * 1024 + c];
  out[idx] = s;
}

extern "C" void kernel_launch(void* const* d_in, const int* in_sizes, int n_in,
                              void* d_out, int out_size, void* d_ws, size_t ws_size,
                              hipStream_t stream) {
  const float* X     = (const float*)d_in[0];
  const float* emb_w = (const float*)d_in[1];
  const float* emb_b = (const float*)d_in[2];
  const float* Wq    = (const float*)d_in[3];
  const float* Wk    = (const float*)d_in[4];
  const float* Wv    = (const float*)d_in[5];
  const float* Wo    = (const float*)d_in[6];
  const float* dec_b = (const float*)d_in[8];
  const float* dec_w = (const float*)d_in[7];
  float* out = (float*)d_out;
  (void)in_sizes; (void)n_in; (void)out_size;

  char* ws = (char*)d_ws;
  // persistent region: 41 MB
  unsigned short* Hbf = (unsigned short*)(ws);                              // 8 MB  [4096][1024]
  unsigned short* Wkq = (unsigned short*)(ws + ((size_t)8 << 20));          // 32 MB [16][1024][1024]
  float* Vb  = (float*)(ws + ((size_t)40 << 20));                          // 256 KB [2][16][2048]
  float* ctx = (float*)(ws + ((size_t)40 << 20) + ((size_t)256 << 10));    // 256 KB [4096][16]
  float* Mw  = (float*)(ws + ((size_t)40 << 20) + ((size_t)512 << 10));    // 64 KB  [16][1024]
  // scratch region S (64 MB), phase-aliased
  char* S = ws + ((size_t)41 << 20);
  unsigned short* Xbf  = (unsigned short*)(S);                              // 4 MB
  unsigned short* EbT  = (unsigned short*)(S + ((size_t)4 << 20));          // 1 MB
  unsigned short* Wqbf = (unsigned short*)(S);                              // 32 MB
  unsigned short* Wkbf = (unsigned short*)(S + ((size_t)32 << 20));         // 32 MB
  unsigned short* G    = (unsigned short*)(S);                              // 64 MB [16][2048][1024]

  const size_t need = ((size_t)41 << 20) + ((size_t)64 << 20);  // 105 MB
  if (ws_size < need) return;  // clean fail -> diagnostic (ws too small)

  cast_bf16<<<2048, 256, 0, stream>>>(X, Xbf, B_ * N_ * IN_DIM_);
  transpose_cast<<<dim3(32, 16, 1), dim3(32, 8), 0, stream>>>(emb_w, EbT, IN_DIM_, D_);
  gemm_embed<<<dim3(8, 32), 256, 0, stream>>>(Xbf, EbT, emb_b, Hbf);
  // Wkq[h] = Wk[h] @ Wq[h]^T  (so that G = h @ Wkq^T = h @ (Wq Wk^T))
  cast_bf16<<<16384, 256, 0, stream>>>(Wq, Wqbf, H_ * D_ * D_);
  cast_bf16<<<16384, 256, 0, stream>>>(Wk, Wkbf, H_ * D_ * D_);
  gemm_nt<<<dim3(8, 8, 16), 256, 0, stream>>>(Wkbf, Wqbf, Wkq, D_,
                                              (long)D_ * D_, (long)D_ * D_, (long)D_ * D_);
  v_kernel<<<1024, 256, 0, stream>>>(Hbf, Wv, Vb);
  wodec_kernel<<<64, 256, 0, stream>>>(Wo, dec_w, Mw);

  for (int b = 0; b < B_; ++b) {
    const unsigned short* Hb = Hbf + (size_t)b * N_ * D_;
    gemm_nt<<<dim3(8, 16, 16), 256, 0, stream>>>(Hb, Wkq, G, D_,
                                                 0L, (long)D_ * D_, (long)N_ * D_);
    flash_kernel<<<dim3(32, 16), 256, 0, stream>>>(G, Hb, Vb + (size_t)b * H_ * N_,
                                                   ctx + (size_t)b * N_ * H_);
  }
  final_kernel<<<16384, 256, 0, stream>>>(ctx, Mw, dec_b, out);
}